// Round 3
// baseline (526.268 us; speedup 1.0000x reference)
//
#include <hip/hip_runtime.h>
#include <stddef.h>

// Problem constants
#define BB   8
#define TT_  2048
#define DD   768
#define VQ_  64
#define L2C  12
#define HID_ 1024
#define KK   4096
#define NMID 4
#define NT   (BB*TT_)         // 16384 positions

typedef _Float16 h8v __attribute__((ext_vector_type(8)));
typedef float    f4v __attribute__((ext_vector_type(4)));

// async global->LDS, 16B per lane, LDS dest = wave-uniform base + lane*16
#define GL16(g, l) __builtin_amdgcn_global_load_lds( \
    (const __attribute__((address_space(1))) void*)(g), \
    (__attribute__((address_space(3))) void*)(l), 16, 0, 0)

// ---------------------------------------------------------------------------
// 1) bits @ mlp_w_in.T + b_in  ->  Y [K, HID]
__global__ __launch_bounds__(256) void k_mlp_in(const float* __restrict__ w_in,
                                                const float* __restrict__ b_in,
                                                float* __restrict__ X) {
    __shared__ float ws_[256 * 12];
    __shared__ float bs_[256];
    int tid = threadIdx.x;
    int h0  = blockIdx.x * 256;
    for (int i = tid; i < 256 * 12; i += 256) ws_[i] = w_in[h0 * 12 + i];
    bs_[tid] = b_in[h0 + tid];
    __syncthreads();
    float w[12];
#pragma unroll
    for (int l = 0; l < 12; l++) w[l] = ws_[tid * 12 + l];
    float bias = bs_[tid];
    int k0 = blockIdx.y * 16;
    for (int kk = 0; kk < 16; kk++) {
        int k = k0 + kk;
        float acc = bias;
#pragma unroll
        for (int l = 0; l < 12; l++)
            if ((k >> (11 - l)) & 1) acc += w[l];
        X[(size_t)k * HID_ + h0 + tid] = acc;
    }
}

// ---------------------------------------------------------------------------
// 2a) BN stats stage 1. grid (64 row-chunks, 4 col-groups), block 256.
// One column per thread, 64 rows ascending — BIT-IDENTICAL per-column chain
// to the validated r8 version. BN stats feed embed feed argmax (knife-edge
// ties, see r7 note at k_argmax_mfma) — do not reorder.
__global__ __launch_bounds__(256) void k_bn_stats1(const float* __restrict__ Y,
                                                   float* __restrict__ part) {
    int b = blockIdx.x;
    int c = blockIdx.y * 256 + threadIdx.x;
    const float* src = Y + ((size_t)b << 6) * HID_ + c;
    float s = 0.f, q = 0.f;
    for (int r = 0; r < 64; r++) {
        float v = src[(size_t)r << 10];
        s += v; q += v * v;
    }
    part[((size_t)b << 10) + c] = s;
    part[65536 + ((size_t)b << 10) + c] = q;
}

// 2b) BN stats stage 2: reduce 64 partials per column -> mean/var. grid 4 x 256
__global__ __launch_bounds__(256) void k_bn_stats2(const float* __restrict__ part,
                                                   float* __restrict__ mv) {
    int c = blockIdx.x * 256 + threadIdx.x;
    float s = 0.f, q = 0.f;
    for (int b = 0; b < 64; b++) {
        s += part[((size_t)b << 10) + c];
        q += part[65536 + ((size_t)b << 10) + c];
    }
    float m = s * (1.f / KK);
    float v = q * (1.f / KK) - m * m;
    mv[c] = m; mv[HID_ + c] = v;
}

// ---------------------------------------------------------------------------
// 3) BN apply + ReLU, emit fp16 hi/lo split pair. grid K*HID/1024, block 256
__global__ __launch_bounds__(256) void k_bn_apply_split(const float* __restrict__ Y,
                                                        const float* __restrict__ mv,
                                                        const float* __restrict__ gamma,
                                                        const float* __restrict__ beta,
                                                        _Float16* __restrict__ Xhi,
                                                        _Float16* __restrict__ Xlo) {
    int i = blockIdx.x * 256 + threadIdx.x;       // float4 index
    int c = (i << 2) & (HID_ - 1);
    float4 x = ((const float4*)Y)[i];
    float4 m = *(const float4*)(mv + c);
    float4 v = *(const float4*)(mv + HID_ + c);
    float4 g = *(const float4*)(gamma + c);
    float4 b = *(const float4*)(beta + c);
    float o[4];
    o[0] = fmaxf(0.f, (x.x - m.x) * (1.f / sqrtf(v.x + 1e-5f)) * g.x + b.x);
    o[1] = fmaxf(0.f, (x.y - m.y) * (1.f / sqrtf(v.y + 1e-5f)) * g.y + b.y);
    o[2] = fmaxf(0.f, (x.z - m.z) * (1.f / sqrtf(v.z + 1e-5f)) * g.z + b.z);
    o[3] = fmaxf(0.f, (x.w - m.w) * (1.f / sqrtf(v.w + 1e-5f)) * g.w + b.w);
    union { _Float16 h[4]; uint2 u; } uh, ul;
#pragma unroll
    for (int j = 0; j < 4; j++) {
        _Float16 h = (_Float16)o[j];
        uh.h[j] = h;
        ul.h[j] = (_Float16)(o[j] - (float)h);
    }
    *(uint2*)(Xhi + ((size_t)i << 2)) = uh.u;
    *(uint2*)(Xlo + ((size_t)i << 2)) = ul.u;
}

// ---------------------------------------------------------------------------
// 4) r12 mid-layer GEMM: C[4096,1024] = (Ahi+Alo) @ (Whi+Wlo)^T + bias.
// Same 128x128 tile / 64x64 wave tile / 64B-row LDS as validated r11 (36 us,
// m97-class 34% efficiency). r12 change: PAIR-step schedule — one vmcnt wait
// + one barrier per TWO K-tiles (sync overhead halved at 1 wave/SIMD).
// 4-buffer rotation: pair p computes bufs {2p&3,(2p+1)&3}; the post-barrier
// STG targets the OTHER pair's bufs, provably consumed at pair p-1 by all
// waves (the barrier proves it). vmcnt(0) at pair start waits only this
// wave's own pair-p loads (issued a full pair earlier, ~1000+ cyc lead).
// Per-element K-chain (t ascending, hh->hl->lh per 32-step, bias after) is
// BIT-IDENTICAL to validated r8/r10/r11 — only the sync cadence changed.
__global__ __launch_bounds__(256) void k_gemm_mfma3(const _Float16* __restrict__ Ahi,
                                                    const _Float16* __restrict__ Alo,
                                                    const _Float16* __restrict__ Whi,
                                                    const _Float16* __restrict__ Wlo,
                                                    const float* __restrict__ bias,
                                                    float* __restrict__ C) {
    __shared__ __attribute__((aligned(128))) char lds[4 * 32768];
    const int tid = threadIdx.x;
    const int wg = blockIdx.x;            // 256 blocks, m-fastest
    const int m0 = (wg & 31) << 7;
    const int n0 = (wg >> 5) << 7;
    const int wave = tid >> 6, lane = tid & 63;
    const int l15 = lane & 15, quad = lane >> 4;
    const int wm = (wave >> 1) << 6;      // 0 / 64
    const int wn = (wave & 1) << 6;       // 0 / 64

    // staging: each wave stages 32 rows of each region (2 x GL16 per region).
    // LDS region layout per 32KB buffer: Ah[0,8K) Al[8K,16K) Wh[16K,24K) Wl[24K,32K)
    const int rowA = (wave << 5) + (lane >> 2);   // 0..127 across waves
    const int colb = (lane & 3) << 4;             // 0/16/32/48 bytes
    const char* gA_h = (const char*)Ahi + ((size_t)(m0 + rowA) << 11) + colb;
    const char* gA_l = (const char*)Alo + ((size_t)(m0 + rowA) << 11) + colb;
    const char* gW_h = (const char*)Whi + ((size_t)(n0 + rowA) << 11) + colb;
    const char* gW_l = (const char*)Wlo + ((size_t)(n0 + rowA) << 11) + colb;
    const int dA = wave << 11;            // wave-uniform LDS dest byte offset

    int offA[4], offW[4];
#pragma unroll
    for (int i = 0; i < 4; i++) offA[i] = ((wm + (i << 4) + l15) << 6) + (quad << 4);
#pragma unroll
    for (int j = 0; j < 4; j++) offW[j] = ((wn + (j << 4) + l15) << 6) + (quad << 4);

    f4v acc[4][4];
#pragma unroll
    for (int i = 0; i < 4; i++)
#pragma unroll
        for (int j = 0; j < 4; j++) acc[i][j] = (f4v){0.f, 0.f, 0.f, 0.f};

#define STG(bufi, tt) do { \
        char* b_ = lds + ((bufi) << 15); int o_ = (tt) << 6; \
        GL16(gA_h + o_,         b_ + dA); \
        GL16(gA_h + 32768 + o_, b_ + dA + 1024); \
        GL16(gA_l + o_,         b_ + 8192 + dA); \
        GL16(gA_l + 32768 + o_, b_ + 8192 + dA + 1024); \
        GL16(gW_h + o_,         b_ + 16384 + dA); \
        GL16(gW_h + 32768 + o_, b_ + 16384 + dA + 1024); \
        GL16(gW_l + o_,         b_ + 24576 + dA); \
        GL16(gW_l + 32768 + o_, b_ + 24576 + dA + 1024); \
    } while (0)

#define CMP(tt) do { \
        const char* b = lds + ((size_t)((tt) & 3) << 15); \
        h8v ah[4], al[4]; \
        _Pragma("unroll") \
        for (int i = 0; i < 4; i++) { \
            ah[i] = *(const h8v*)(b + offA[i]); \
            al[i] = *(const h8v*)(b + 8192 + offA[i]); \
        } \
        __builtin_amdgcn_s_setprio(1); \
        _Pragma("unroll") \
        for (int j = 0; j < 4; j++) { \
            h8v bh = *(const h8v*)(b + 16384 + offW[j]); \
            h8v bl = *(const h8v*)(b + 24576 + offW[j]); \
            _Pragma("unroll") \
            for (int i = 0; i < 4; i++) { \
                acc[i][j] = __builtin_amdgcn_mfma_f32_16x16x32_f16(ah[i], bh, acc[i][j], 0, 0, 0); \
                acc[i][j] = __builtin_amdgcn_mfma_f32_16x16x32_f16(ah[i], bl, acc[i][j], 0, 0, 0); \
                acc[i][j] = __builtin_amdgcn_mfma_f32_16x16x32_f16(al[i], bh, acc[i][j], 0, 0, 0); \
            } \
        } \
        __builtin_amdgcn_s_setprio(0); \
    } while (0)

    STG(0, 0); STG(1, 1);                 // pair 0 in flight
    for (int p = 0; p < 16; ++p) {
        asm volatile("s_waitcnt vmcnt(0)" ::: "memory");   // own pair-p loads done
        __builtin_amdgcn_s_barrier();     // all waves' pair-p loads visible;
                                          // pair p-1 bufs fully consumed
        asm volatile("" ::: "memory");
        if (p < 15) { STG((2 * p + 2) & 3, 2 * p + 2); STG((2 * p + 3) & 3, 2 * p + 3); }
        CMP(2 * p);
        CMP(2 * p + 1);
        asm volatile("" ::: "memory");
    }
#undef CMP
#undef STG

#pragma unroll
    for (int j = 0; j < 4; j++) {
        int col = n0 + wn + (j << 4) + l15;
        float bv = bias[col];
#pragma unroll
        for (int i = 0; i < 4; i++) {
            int row = m0 + wm + (i << 4) + (quad << 2);
#pragma unroll
            for (int r = 0; r < 4; r++)
                C[(size_t)(row + r) * HID_ + col] = acc[i][j][r] + bv;
        }
    }
}

// ---------------------------------------------------------------------------
// 4b) out-layer GEMM (N=64): validated r10 kernel, tile 128x64. Kept for the
// w_out layer only (N=64 can't fill a 128x128 tile). grid 32 (mult of 8).
__global__ __launch_bounds__(256) void k_gemm_mfma2(const _Float16* __restrict__ Ahi,
                                                    const _Float16* __restrict__ Alo,
                                                    const _Float16* __restrict__ Whi,
                                                    const _Float16* __restrict__ Wlo,
                                                    const float* __restrict__ bias,
                                                    float* __restrict__ C,
                                                    int M, int N, int Kd) {
    __shared__ __attribute__((aligned(128))) char lds[2][24576];
    const int tid = threadIdx.x;
    int wg = blockIdx.x;
    const int nwg = gridDim.x;           // multiple of 8
    wg = (wg & 7) * (nwg >> 3) + (wg >> 3);
    const int nx = M >> 7;
    const int m0 = (wg % nx) << 7;
    const int n0 = (wg / nx) << 6;
    const int wave = tid >> 6, lane = tid & 63;
    const int l15 = lane & 15, quad = lane >> 4;
    const int wm = (wave >> 1) << 6;      // 0 / 64
    const int wn = (wave & 1) << 5;       // 0 / 32

    const int pA0 = ((wave << 1) | 0) * 1024 + lane * 16;
    const int pA1 = ((wave << 1) | 1) * 1024 + lane * 16;
    const int pW  = wave * 1024 + lane * 16;
    const int qA0 = pA0 ^ (((pA0 >> 7) & 3) << 4);
    const int qA1 = pA1 ^ (((pA1 >> 7) & 3) << 4);
    const int qW  = pW  ^ (((pW  >> 7) & 3) << 4);
    const size_t krow = (size_t)Kd * 2;
    const char* gAh0 = (const char*)Ahi + (size_t)(m0 + (qA0 >> 6)) * krow + (qA0 & 63);
    const char* gAh1 = (const char*)Ahi + (size_t)(m0 + (qA1 >> 6)) * krow + (qA1 & 63);
    const char* gAl0 = (const char*)Alo + (size_t)(m0 + (qA0 >> 6)) * krow + (qA0 & 63);
    const char* gAl1 = (const char*)Alo + (size_t)(m0 + (qA1 >> 6)) * krow + (qA1 & 63);
    const char* gWh  = (const char*)Whi + (size_t)(n0 + (qW >> 6)) * krow + (qW & 63);
    const char* gWl  = (const char*)Wlo + (size_t)(n0 + (qW >> 6)) * krow + (qW & 63);
    const int dA0 = (wave << 1) * 1024;
    const int dA1 = dA0 + 1024;
    const int dW  = wave * 1024;

    int offA[4], offW[2];
#pragma unroll
    for (int i = 0; i < 4; i++) {
        int r = wm + (i << 4) + l15;
        offA[i] = r * 64 + ((quad ^ ((r >> 1) & 3)) << 4);
    }
#pragma unroll
    for (int j = 0; j < 2; j++) {
        int r = wn + (j << 4) + l15;
        offW[j] = r * 64 + ((quad ^ ((r >> 1) & 3)) << 4);
    }

    f4v acc[4][2];
#pragma unroll
    for (int i = 0; i < 4; i++)
#pragma unroll
        for (int j = 0; j < 2; j++) acc[i][j] = (f4v){0.f, 0.f, 0.f, 0.f};

#define STAGE(bufi, tt) do { \
        char* b_ = lds[bufi]; size_t o_ = (size_t)(tt) << 6; \
        GL16(gAh0 + o_, b_ + dA0); \
        GL16(gAh1 + o_, b_ + dA1); \
        GL16(gAl0 + o_, b_ + 8192 + dA0); \
        GL16(gAl1 + o_, b_ + 8192 + dA1); \
        GL16(gWh  + o_, b_ + 16384 + dW); \
        GL16(gWl  + o_, b_ + 20480 + dW); \
    } while (0)

    STAGE(0, 0);
    const int nt = Kd >> 5;
    for (int t = 0; t < nt; ++t) {
        const int cur = t & 1;
        if (t + 1 < nt) {
            STAGE(cur ^ 1, t + 1);
            asm volatile("s_waitcnt vmcnt(6)" ::: "memory");
        } else {
            asm volatile("s_waitcnt vmcnt(0)" ::: "memory");
        }
        __builtin_amdgcn_s_barrier();
        asm volatile("" ::: "memory");
        const char* b = lds[cur];
        h8v ah[4], al[4], bh[2], bl[2];
#pragma unroll
        for (int i = 0; i < 4; i++) {
            ah[i] = *(const h8v*)(b + offA[i]);
            al[i] = *(const h8v*)(b + 8192 + offA[i]);
        }
#pragma unroll
        for (int j = 0; j < 2; j++) {
            bh[j] = *(const h8v*)(b + 16384 + offW[j]);
            bl[j] = *(const h8v*)(b + 20480 + offW[j]);
        }
        __builtin_amdgcn_s_setprio(1);
#pragma unroll
        for (int i = 0; i < 4; i++)
#pragma unroll
            for (int j = 0; j < 2; j++) {
                acc[i][j] = __builtin_amdgcn_mfma_f32_16x16x32_f16(ah[i], bh[j], acc[i][j], 0, 0, 0);
                acc[i][j] = __builtin_amdgcn_mfma_f32_16x16x32_f16(ah[i], bl[j], acc[i][j], 0, 0, 0);
                acc[i][j] = __builtin_amdgcn_mfma_f32_16x16x32_f16(al[i], bh[j], acc[i][j], 0, 0, 0);
            }
        __builtin_amdgcn_s_setprio(0);
        asm volatile("" ::: "memory");
        __builtin_amdgcn_s_barrier();
    }
#undef STAGE

#pragma unroll
    for (int j = 0; j < 2; j++) {
        int col = n0 + wn + (j << 4) + l15;
        float bv = bias[col];
#pragma unroll
        for (int i = 0; i < 4; i++) {
            int row = m0 + wm + (i << 4) + (quad << 2);
#pragma unroll
            for (int r = 0; r < 4; r++)
                C[(size_t)(row + r) * N + col] = acc[i][j][r] + bv;
        }
    }
}

// ---------------------------------------------------------------------------
// 5) L2-normalize embed rows (in place) + f16 split + eqh = -0.5*||ehat||^2
__global__ __launch_bounds__(256) void k_l2norm(float* __restrict__ E,
                                                float* __restrict__ eqh,
                                                _Float16* __restrict__ Ehi,
                                                _Float16* __restrict__ Elo) {
    int tid = threadIdx.x;
    int row = blockIdx.x * 4 + (tid >> 6);
    int v = tid & 63;
    size_t off = ((size_t)row << 6) + v;
    float x = E[off];
    float ss = x * x;
#pragma unroll
    for (int o = 32; o; o >>= 1) ss += __shfl_xor(ss, o, 64);
    float inv = 1.f / (sqrtf(ss) + 1e-6f);
    float xn = x * inv;
    E[off] = xn;
    _Float16 hh = (_Float16)xn;
    Ehi[off] = hh;
    Elo[off] = (_Float16)(xn - (float)hh);
    if (v == 0) eqh[row] = -0.5f * (ss * inv * inv);
}

// ---------------------------------------------------------------------------
// 6a) r12: ALL fp32->f16 hi/lo weight splits in ONE launch (w_mid 4 layers,
// w_out, proj_w) — same per-element rounding as the old k_wsplit, so the
// chain stays bit-exact. Runs once at t=0; removes 5 launches from the
// serial stream. Segments (float4 units): [0,1048576) w_mid, then 16384
// w_out, then 12288 proj_w. grid 4208 x 256.
__global__ __launch_bounds__(256) void k_wsplit_all(const float* __restrict__ w_mid,
                                                    const float* __restrict__ w_out,
                                                    const float* __restrict__ proj_w,
                                                    _Float16* __restrict__ Wmh,
                                                    _Float16* __restrict__ Wml,
                                                    _Float16* __restrict__ Woh,
                                                    _Float16* __restrict__ Wol,
                                                    _Float16* __restrict__ pwhi,
                                                    _Float16* __restrict__ pwlo) {
    int i = blockIdx.x * 256 + threadIdx.x;
    const float4* src; _Float16 *dh, *dl; int off;
    if (i < 1048576)            { src = (const float4*)w_mid;  dh = Wmh;  dl = Wml;  off = i; }
    else if (i < 1048576+16384) { src = (const float4*)w_out;  dh = Woh;  dl = Wol;  off = i - 1048576; }
    else                        { src = (const float4*)proj_w; dh = pwhi; dl = pwlo; off = i - 1048576 - 16384; }
    float4 w = src[off];
    float wf[4] = {w.x, w.y, w.z, w.w};
    union { _Float16 h[4]; uint2 u; } uh, ul;
#pragma unroll
    for (int j = 0; j < 4; j++) {
        _Float16 h = (_Float16)wf[j];
        uh.h[j] = h;
        ul.h[j] = (_Float16)(wf[j] - (float)h);
    }
    *(uint2*)(dh + ((size_t)off << 2)) = uh.u;
    *(uint2*)(dl + ((size_t)off << 2)) = ul.u;
}

// 6a') convert inv_w -> f16 hi only [d][v] (final projection is not
// argmax-feeding; threshold 81.92 >> f16 error). grid 48 x 256.
// iwh lives in the OVERLAY region (dead Xhi/Xlo) — must stay a LATE launch
// (overlay invalid before the out-layer GEMM; and the r8-proven ws
// high-water mark must not grow — r9 died extending it).
__global__ __launch_bounds__(256) void k_cvt_inv(const float* __restrict__ iw,
                                                 _Float16* __restrict__ iwh) {
    int i = blockIdx.x * 256 + threadIdx.x;       // float4 index, 49152/4 total
    float4 w = ((const float4*)iw)[i];
    union { _Float16 h[4]; uint2 u; } uh;
    uh.h[0] = (_Float16)w.x; uh.h[1] = (_Float16)w.y;
    uh.h[2] = (_Float16)w.z; uh.h[3] = (_Float16)w.w;
    *(uint2*)(iwh + ((size_t)i << 2)) = uh.u;
}

// ---------------------------------------------------------------------------
// 6b) projection GEMM, split-K: Hpart[ks][t][v] = sum_{d in chunk} h_in[b,d,t]*pw[v,d]
// grid (NT/128, 4), block 256 (4 waves, each 32t x 64v). 6 K-steps of 32.
__global__ __launch_bounds__(256) void k_proj_mfma(const float* __restrict__ h_in,
                                                   const _Float16* __restrict__ pwhi,
                                                   const _Float16* __restrict__ pwlo,
                                                   float* __restrict__ Hpart) {
    __shared__ float shA[128 * 33];
    const int tid = threadIdx.x;
    const int t0 = blockIdx.x * 128;
    const int ks = blockIdx.y;            // d-chunk [ks*192, ks*192+192)
    const int b = t0 >> 11;
    const int tloc0 = t0 & (TT_ - 1);
    const int wave = tid >> 6, lane = tid & 63;
    const int l15 = lane & 15, quad = lane >> 4;

    const int dl = tid >> 3;              // 0..31 (d within chunk step)
    const int tg = (tid & 7) << 4;        // 0,16,...,112 (t offset)

    f4v acc[2][4];
#pragma unroll
    for (int i = 0; i < 2; i++)
#pragma unroll
        for (int j = 0; j < 4; j++) acc[i][j] = (f4v){0.f, 0.f, 0.f, 0.f};

    for (int kk = 0; kk < 6; kk++) {
        int dd0 = ks * 192 + kk * 32;
        const float* src = h_in + ((size_t)(b * DD + dd0 + dl) << 11) + tloc0 + tg;
        float4 g0 = *(const float4*)(src);
        float4 g1 = *(const float4*)(src + 4);
        float4 g2 = *(const float4*)(src + 8);
        float4 g3 = *(const float4*)(src + 12);
        __syncthreads();
        float gv[16] = {g0.x, g0.y, g0.z, g0.w, g1.x, g1.y, g1.z, g1.w,
                        g2.x, g2.y, g2.z, g2.w, g3.x, g3.y, g3.z, g3.w};
#pragma unroll
        for (int i = 0; i < 16; i++) shA[(tg + i) * 33 + dl] = gv[i];
        __syncthreads();

        h8v ah[2], al[2];
#pragma unroll
        for (int mt = 0; mt < 2; mt++) {
            const float* ap = &shA[((wave << 5) + (mt << 4) + l15) * 33 + (quad << 3)];
            float4 a0 = *(const float4*)(ap);
            float4 a1 = *(const float4*)(ap + 4);
            float av[8] = {a0.x, a0.y, a0.z, a0.w, a1.x, a1.y, a1.z, a1.w};
#pragma unroll
            for (int j = 0; j < 8; j++) {
                _Float16 h = (_Float16)av[j];
                ah[mt][j] = h;
                al[mt][j] = (_Float16)(av[j] - (float)h);
            }
        }
#pragma unroll
        for (int nt = 0; nt < 4; nt++) {
            size_t wb = (size_t)((nt << 4) + l15) * DD + dd0 + (quad << 3);
            h8v bh = *(const h8v*)(pwhi + wb);
            h8v bl = *(const h8v*)(pwlo + wb);
#pragma unroll
            for (int mt = 0; mt < 2; mt++) {
                acc[mt][nt] = __builtin_amdgcn_mfma_f32_16x16x32_f16(ah[mt], bh, acc[mt][nt], 0, 0, 0);
                acc[mt][nt] = __builtin_amdgcn_mfma_f32_16x16x32_f16(ah[mt], bl, acc[mt][nt], 0, 0, 0);
                acc[mt][nt] = __builtin_amdgcn_mfma_f32_16x16x32_f16(al[mt], bh, acc[mt][nt], 0, 0, 0);
            }
        }
    }
    float* dst = Hpart + ((size_t)ks << 20);   // ks*16384*64
#pragma unroll
    for (int mt = 0; mt < 2; mt++) {
#pragma unroll
        for (int r = 0; r < 4; r++) {
            int t = t0 + (wave << 5) + (mt << 4) + (quad << 2) + r;
#pragma unroll
            for (int nt = 0; nt < 4; nt++)
                dst[((size_t)t << 6) + (nt << 4) + l15] = acc[mt][nt][r];
        }
    }
}

// ---------------------------------------------------------------------------
// 6c) sum 4 partials + bias, L2-normalize, f16 split. grid NT/64, block 256
__global__ __launch_bounds__(256) void k_hnorm(const float* __restrict__ Hpart,
                                               const float* __restrict__ pb,
                                               _Float16* __restrict__ Hhi,
                                               _Float16* __restrict__ Hlo) {
    __shared__ float ssp[4][64];
    int tid = threadIdx.x;
    int tt = tid & 63, vg = tid >> 6;
    int t = blockIdx.x * 64 + tt;
    size_t base = ((size_t)t << 6) + (vg << 4);
    float o[16];
#pragma unroll
    for (int u = 0; u < 4; u++) {
        float4 p0 = *(const float4*)(Hpart + (0u << 20) + base + (u << 2));
        float4 p1 = *(const float4*)(Hpart + (1u << 20) + base + (u << 2));
        float4 p2 = *(const float4*)(Hpart + (2u << 20) + base + (u << 2));
        float4 p3 = *(const float4*)(Hpart + (3u << 20) + base + (u << 2));
        o[u * 4 + 0] = p0.x + p1.x + p2.x + p3.x;
        o[u * 4 + 1] = p0.y + p1.y + p2.y + p3.y;
        o[u * 4 + 2] = p0.z + p1.z + p2.z + p3.z;
        o[u * 4 + 3] = p0.w + p1.w + p2.w + p3.w;
    }
    float sp = 0.f;
#pragma unroll
    for (int j = 0; j < 16; j++) {
        o[j] += pb[(vg << 4) + j];
        sp = fmaf(o[j], o[j], sp);
    }
    ssp[vg][tt] = sp;
    __syncthreads();
    float ss = ssp[0][tt] + ssp[1][tt] + ssp[2][tt] + ssp[3][tt];
    float inv = 1.f / (sqrtf(ss) + 1e-6f);
    union { _Float16 h[8]; uint4 u; } uh0, uh1, ul0, ul1;
#pragma unroll
    for (int j = 0; j < 16; j++) {
        float xn = o[j] * inv;
        _Float16 hh = (_Float16)xn;
        _Float16 ll = (_Float16)(xn - (float)hh);
        if (j < 8) { uh0.h[j] = hh; ul0.h[j] = ll; }
        else       { uh1.h[j - 8] = hh; ul1.h[j - 8] = ll; }
    }
    *(uint4*)(Hhi + base)     = uh0.u;
    *(uint4*)(Hhi + base + 8) = uh1.u;
    *(uint4*)(Hlo + base)     = ul0.u;
    *(uint4*)(Hlo + base + 8) = ul1.u;
}

// ---------------------------------------------------------------------------
// 7) MFMA argmax: s'(t,k) = hhat.ehat + (-0.5*||ehat||^2).
// NOTE: dot MUST be accumulated from zero-init C and q added AFTER — this
// rounding order is bit-matched to the validated r6 kernel. Folding q into
// the C init (r7) perturbed near-ties between codebook rows at distant
// indices and flipped vq_code. Do not reassociate.
// r12 restructure (math-neutral; r2 diagnosis: 48.5us latency-bound, 55%
// no-issue, VGPR=64 => compiler was RELOADING H fragments every iter):
// wave t-tile halved to 32 (H = 8 h8v = 32 VGPR, stays resident), grid
// doubled to (NT/128, 16) = 2048 blocks (8 blocks/CU TLP), E-tiles
// prefetched 2 DEEP (two register sets), setprio around MFMA clusters.
// Per-(t,k) MFMA term order + k-ascending select order unchanged.
__global__ __launch_bounds__(256) void k_argmax_mfma(const _Float16* __restrict__ Hhi,
                                                     const _Float16* __restrict__ Hlo,
                                                     const _Float16* __restrict__ Ehi,
                                                     const _Float16* __restrict__ Elo,
                                                     const float* __restrict__ eqh,
                                                     float* __restrict__ ps,
                                                     int* __restrict__ pi) {
    int tid = threadIdx.x;
    int wave = tid >> 6, lane = tid & 63;
    int l15 = lane & 15, quad = lane >> 4;
    int t0 = blockIdx.x * 128 + wave * 32;
    int kh = blockIdx.y;                  // 0..15, k-range [kh*256, kh*256+256)
    const int kbase = kh << 8;

    h8v hh0[2], hh1[2], hl0[2], hl1[2];
#pragma unroll
    for (int s = 0; s < 2; s++) {
        size_t hb = (size_t)(t0 + (s << 4) + l15) * 64 + (quad << 3);
        hh0[s] = *(const h8v*)(Hhi + hb);
        hh1[s] = *(const h8v*)(Hhi + hb + 32);
        hl0[s] = *(const h8v*)(Hlo + hb);
        hl1[s] = *(const h8v*)(Hlo + hb + 32);
    }
    float best[2] = {-1e30f, -1e30f};
    int   idx[2]  = {0, 0};

    // 2-deep prefetch: tiles 0 and 1 in two register sets
    size_t eb0 = (size_t)(kbase + l15) * 64 + (quad << 3);
    h8v e0h0 = *(const h8v*)(Ehi + eb0);
    h8v e0h1 = *(const h8v*)(Ehi + eb0 + 32);
    h8v e0l0 = *(const h8v*)(Elo + eb0);
    h8v e0l1 = *(const h8v*)(Elo + eb0 + 32);
    float4 q0 = *(const float4*)(eqh + kbase + (quad << 2));
    size_t eb1 = eb0 + 1024;              // +16 rows * 64 f16
    h8v e1h0 = *(const h8v*)(Ehi + eb1);
    h8v e1h1 = *(const h8v*)(Ehi + eb1 + 32);
    h8v e1l0 = *(const h8v*)(Elo + eb1);
    h8v e1l1 = *(const h8v*)(Elo + eb1 + 32);
    float4 q1 = *(const float4*)(eqh + kbase + 16 + (quad << 2));

    // per-element chain identical to r6-validated order:
    // (ehi0*hh0) (ehi1*hh1) (elo0*hh0) (elo1*hh1) (ehi0*hl0) (ehi1*hl1), +q after
#define AHALF(EH0, EH1, EL0, EL1, QQ, IT) do { \
        f4v acc0 = (f4v){0.f, 0.f, 0.f, 0.f}; \
        f4v acc1 = (f4v){0.f, 0.f, 0.f, 0.f}; \
        __builtin_amdgcn_s_setprio(1); \
        acc0 = __builtin_amdgcn_mfma_f32_16x16x32_f16(EH0, hh0[0], acc0, 0, 0, 0); \
        acc1 = __builtin_amdgcn_mfma_f32_16x16x32_f16(EH0, hh0[1], acc1, 0, 0, 0); \
        acc0 = __builtin_amdgcn_mfma_f32_16x16x32_f16(EH1, hh1[0], acc0, 0, 0, 0); \
        acc1 = __builtin_amdgcn_mfma_f32_16x16x32_f16(EH1, hh1[1], acc1, 0, 0, 0); \
        acc0 = __builtin_amdgcn_mfma_f32_16x16x32_f16(EL0, hh0[0], acc0, 0, 0, 0); \
        acc1 = __builtin_amdgcn_mfma_f32_16x16x32_f16(EL0, hh0[1], acc1, 0, 0, 0); \
        acc0 = __builtin_amdgcn_mfma_f32_16x16x32_f16(EL1, hh1[0], acc0, 0, 0, 0); \
        acc1 = __builtin_amdgcn_mfma_f32_16x16x32_f16(EL1, hh1[1], acc1, 0, 0, 0); \
        acc0 = __builtin_amdgcn_mfma_f32_16x16x32_f16(EH0, hl0[0], acc0, 0, 0, 0); \
        acc1 = __builtin_amdgcn_mfma_f32_16x16x32_f16(EH0, hl0[1], acc1, 0, 0, 0); \
        acc0 = __builtin_amdgcn_mfma_f32_16x16x32_f16(EH1, hl1[0], acc0, 0, 0, 0); \
        acc1 = __builtin_amdgcn_mfma_f32_16x16x32_f16(EH1, hl1[1], acc1, 0, 0, 0); \
        __builtin_amdgcn_s_setprio(0); \
        float cqa[4] = {QQ.x, QQ.y, QQ.z, QQ.w}; \
        int tn = (IT) + 2; if (tn > 15) tn = 15;      /* clamp: redundant-but-valid */ \
        size_t ebn = (size_t)(kbase + (tn << 4) + l15) * 64 + (quad << 3); \
        EH0 = *(const h8v*)(Ehi + ebn); \
        EH1 = *(const h8v*)(Ehi + ebn + 32); \
        EL0 = *(const h8v*)(Elo + ebn); \
        EL1 = *(const h8v*)(Elo + ebn + 32); \
        QQ  = *(const float4*)(eqh + kbase + (tn << 4) + (quad << 2)); \
        int k0 = kbase + ((IT) << 4); \
        _Pragma("unroll") \
        for (int r = 0; r < 4; r++) { \
            int kk_ = k0 + (quad << 2) + r; \
            float sc0 = acc0[r] + cqa[r]; \
            if (sc0 > best[0]) { best[0] = sc0; idx[0] = kk_; } \
            float sc1 = acc1[r] + cqa[r]; \
            if (sc1 > best[1]) { best[1] = sc1; idx[1] = kk_; } \
        } \
    } while (0)

    for (int p = 0; p < 8; ++p) {
        AHALF(e0h0, e0h1, e0l0, e0l1, q0, 2 * p);
        AHALF(e1h0, e1h1, e1l0, e1l1, q1, 2 * p + 1);
    }
#undef AHALF

#pragma unroll
    for (int m = 16; m <= 32; m <<= 1) {
#pragma unroll
        for (int s = 0; s < 2; s++) {
            float ob = __shfl_xor(best[s], m, 64);
            int   oi = __shfl_xor(idx[s], m, 64);
            if (ob > best[s] || (ob == best[s] && oi < idx[s])) { best[s] = ob; idx[s] = oi; }
        }
    }
    if (quad == 0) {
#pragma unroll
        for (int s = 0; s < 2; s++) {
            int t = t0 + (s << 4) + l15;
            ps[(size_t)t * 16 + kh] = best[s];
            pi[(size_t)t * 16 + kh] = idx[s];
        }
    }
}

// ---------------------------------------------------------------------------
// 8) merge 16 partials -> code; write vq_code (fp32, masked); gather G16 (f16)
__global__ __launch_bounds__(256) void k_merge(const float* __restrict__ ps,
                                               const int* __restrict__ pi,
                                               const int* __restrict__ mask,
                                               const _Float16* __restrict__ Ehi,
                                               _Float16* __restrict__ G16,
                                               float* __restrict__ outc) {
    __shared__ int codes[256];
    __shared__ int ms[256];
    int tid = threadIdx.x;
    int base = blockIdx.x << 8;
    int t = base + tid;
    float best = ps[(size_t)t * 16];
    int bi = pi[(size_t)t * 16];
#pragma unroll
    for (int s = 1; s < 16; s++) {
        float v = ps[(size_t)t * 16 + s];
        if (v > best) { best = v; bi = pi[(size_t)t * 16 + s]; }
    }
    int m = mask[t];
    codes[tid] = bi;
    ms[tid] = m;
    outc[t] = m ? (float)bi : 0.0f;
    __syncthreads();
    // 64 f16 per row = 8 uint4
    for (int i = tid; i < 256 * 8; i += 256) {
        int r = i >> 3, u = i & 7;
        uint4 e = ms[r] ? ((const uint4*)(Ehi + ((size_t)codes[r] << 6)))[u]
                        : make_uint4(0u, 0u, 0u, 0u);
        ((uint4*)(G16 + ((size_t)(base + r) << 6)))[u] = e;
    }
}

// ---------------------------------------------------------------------------
// 9) final projection: out_q[t][d] = sum_v G16[t][v]*iwh[d][v] + inv_b[d]
// 1-term f16 MFMA (not argmax-feeding; threshold very loose).
// grid (NT/128, DD/64), block 256 (4 waves, each 32t x 64d). K=64 (2 steps).
__global__ __launch_bounds__(256) void k_gemm_out(const _Float16* __restrict__ G16,
                                                  const _Float16* __restrict__ iwh,
                                                  const float* __restrict__ bias,
                                                  float* __restrict__ C) {
    const int tid = threadIdx.x;
    const int t0 = blockIdx.x * 128, n0 = blockIdx.y * 64;
    const int wave = tid >> 6, lane = tid & 63;
    const int l15 = lane & 15, quad = lane >> 4;

    f4v acc[2][4];
#pragma unroll
    for (int i = 0; i < 2; i++)
#pragma unroll
        for (int j = 0; j < 4; j++) acc[i][j] = (f4v){0.f, 0.f, 0.f, 0.f};

#pragma unroll
    for (int ks = 0; ks < 2; ks++) {
        int kk = (ks << 5) + (quad << 3);
        h8v a[2], b[4];
#pragma unroll
        for (int mt = 0; mt < 2; mt++)
            a[mt] = *(const h8v*)(G16 + (size_t)(t0 + (wave << 5) + (mt << 4) + l15) * 64 + kk);
#pragma unroll
        for (int nt = 0; nt < 4; nt++)
            b[nt] = *(const h8v*)(iwh + (size_t)(n0 + (nt << 4) + l15) * 64 + kk);
#pragma unroll
        for (int mt = 0; mt < 2; mt++)
#pragma unroll
            for (int nt = 0; nt < 4; nt++)
                acc[mt][nt] = __builtin_amdgcn_mfma_f32_16x16x32_f16(a[mt], b[nt], acc[mt][nt], 0, 0, 0);
    }
#pragma unroll
    for (int nt = 0; nt < 4; nt++) {
        int col = n0 + (nt << 4) + l15;
        float bv = bias[col];
#pragma unroll
        for (int mt = 0; mt < 2; mt++) {
            int row = t0 + (wave << 5) + (mt << 4) + (quad << 2);
#pragma unroll
            for (int r = 0; r < 4; r++)
                C[(size_t)(row + r) * DD + col] = acc[mt][nt][r] + bv;
        }
    }
}

// ---------------------------------------------------------------------------
extern "C" void kernel_launch(void* const* d_in, const int* in_sizes, int n_in,
                              void* d_out, int out_size, void* d_ws, size_t ws_size,
                              hipStream_t stream) {
    const float* h_in   = (const float*)d_in[0];
    const int*   amask  = (const int*)d_in[1];
    const float* proj_w = (const float*)d_in[2];
    const float* proj_b = (const float*)d_in[3];
    const float* inv_w  = (const float*)d_in[4];
    const float* inv_b  = (const float*)d_in[5];
    const float* w_in   = (const float*)d_in[6];
    const float* b_in   = (const float*)d_in[7];
    const float* w_mid  = (const float*)d_in[8];
    const float* b_mid  = (const float*)d_in[9];
    const float* w_out  = (const float*)d_in[10];
    const float* b_out  = (const float*)d_in[11];
    const float* gamma  = (const float*)d_in[12];
    const float* beta   = (const float*)d_in[13];

    // static region (high-water mark == r8-proven footprint; do NOT extend)
    float*     Y    = (float*)d_ws;                          // K*HID fp32   (16 MB)
    _Float16*  Xhi  = (_Float16*)(Y + (size_t)KK * HID_);    // K*HID fp16   (8 MB)
    _Float16*  Xlo  = Xhi + (size_t)KK * HID_;               // K*HID fp16   (8 MB)
    float*     mv   = (float*)(Xlo + (size_t)KK * HID_);     // 2*HID
    float*     Emb  = mv + 2 * HID_;                         // K*VQ fp32
    float*     eqh  = Emb + (size_t)KK * VQ_;                // K
    float*     spart= eqh + KK;                              // 2*64*1024 stats partials
    _Float16*  pwhi = (_Float16*)(spart + 2 * 65536);        // VQ*DD f16
    _Float16*  pwlo = pwhi + (size_t)VQ_ * DD;               // VQ*DD f16  <- ws END (r8 level)
    // overlays (inside dead Xhi/Xlo region, valid after the out-layer GEMM):
    float*    Hpart = Y;                                     // 4*NT*64 fp32 == K*HID exactly
    _Float16* H16hi = Xhi;                                   // NT*64 f16
    _Float16* H16lo = H16hi + (size_t)NT * VQ_;              // NT*64 f16
    _Float16* E16hi = H16lo + (size_t)NT * VQ_;              // K*64 f16
    _Float16* E16lo = E16hi + (size_t)KK * VQ_;              // K*64 f16
    float*    ps    = (float*)(E16lo + (size_t)KK * VQ_);    // NT*16
    int*      pidx  = (int*)(ps + (size_t)NT * 16);          // NT*16
    _Float16* G16   = (_Float16*)(pidx + (size_t)NT * 16);   // NT*64 f16
    _Float16* iwh   = G16 + (size_t)NT * VQ_;                // DD*VQ f16 (overlay, not ws end)

    float* out_q = (float*)d_out;                            // NT*DD fp32
    float* out_c = out_q + (size_t)NT * DD;                  // NT fp32

    // pre-split weights into the d_out region (dead as scratch until
    // k_gemm_out fully overwrites it at the end; avoids touching the
    // r8-proven ws high-water mark). 16.25 MB of 48 MB used.
    _Float16* Wmh = (_Float16*)d_out;                        // 4*HID*HID f16 (8 MB)
    _Float16* Wml = Wmh + (size_t)NMID * HID_ * HID_;        // 4*HID*HID f16 (8 MB)
    _Float16* Woh = Wml + (size_t)NMID * HID_ * HID_;        // VQ*HID f16 (128 KB)
    _Float16* Wol = Woh + (size_t)VQ_ * HID_;                // VQ*HID f16 (128 KB)

    // all fp32->f16 weight splits in one launch (w_mid x4, w_out, proj_w)
    k_wsplit_all<<<4208, 256, 0, stream>>>(w_mid, w_out, proj_w,
                                           Wmh, Wml, Woh, Wol, pwhi, pwlo);

    // codebook MLP (fp16-split MFMA chain, fp32-equivalent precision)
    k_mlp_in<<<dim3(HID_ / 256, KK / 16), 256, 0, stream>>>(w_in, b_in, Y);
    k_bn_stats1<<<dim3(64, 4), 256, 0, stream>>>(Y, spart);
    k_bn_stats2<<<4, 256, 0, stream>>>(spart, mv);
    k_bn_apply_split<<<KK * HID_ / 1024, 256, 0, stream>>>(Y, mv, gamma, beta, Xhi, Xlo);
    for (int i = 0; i < NMID; i++) {
        k_gemm_mfma3<<<(KK / 128) * (HID_ / 128), 256, 0, stream>>>(
            Xhi, Xlo, Wmh + (size_t)i * HID_ * HID_, Wml + (size_t)i * HID_ * HID_,
            b_mid + (size_t)i * HID_, Y);
        k_bn_stats1<<<dim3(64, 4), 256, 0, stream>>>(Y, spart);
        k_bn_stats2<<<4, 256, 0, stream>>>(spart, mv);
        k_bn_apply_split<<<KK * HID_ / 1024, 256, 0, stream>>>(Y, mv,
            gamma + (size_t)(i + 1) * HID_, beta + (size_t)(i + 1) * HID_, Xhi, Xlo);
    }
    k_gemm_mfma2<<<(KK / 128) * (VQ_ / 64), 256, 0, stream>>>(
        Xhi, Xlo, Woh, Wol, b_out, Emb, KK, VQ_, HID_);
    k_l2norm<<<KK / 4, 256, 0, stream>>>(Emb, eqh, E16hi, E16lo);

    // hidden-state path (Xhi/Xlo dead from here; overlay region valid)
    k_cvt_inv<<<VQ_ * DD / 1024, 256, 0, stream>>>(inv_w, iwh);
    k_proj_mfma<<<dim3(NT / 128, 4), 256, 0, stream>>>(h_in, pwhi, pwlo, Hpart);
    k_hnorm<<<NT / 64, 256, 0, stream>>>(Hpart, proj_b, H16hi, H16lo);
    k_argmax_mfma<<<dim3(NT / 128, 16), 256, 0, stream>>>(
        H16hi, H16lo, E16hi, E16lo, eqh, ps, pidx);
    k_merge<<<NT / 256, 256, 0, stream>>>(ps, pidx, amask, E16hi, G16, out_c);
    k_gemm_out<<<dim3(NT / 128, DD / 64), 256, 0, stream>>>(G16, iwh, inv_b, out_q);
}

// Round 4
// 453.323 us; speedup vs baseline: 1.1609x; 1.1609x over previous
//
#include <hip/hip_runtime.h>
#include <stddef.h>

// Problem constants
#define BB   8
#define TT_  2048
#define DD   768
#define VQ_  64
#define L2C  12
#define HID_ 1024
#define KK   4096
#define NMID 4
#define NT   (BB*TT_)         // 16384 positions

typedef _Float16 h8v __attribute__((ext_vector_type(8)));
typedef float    f4v __attribute__((ext_vector_type(4)));

// async global->LDS, 16B per lane, LDS dest = wave-uniform base + lane*16
#define GL16(g, l) __builtin_amdgcn_global_load_lds( \
    (const __attribute__((address_space(1))) void*)(g), \
    (__attribute__((address_space(3))) void*)(l), 16, 0, 0)

// ---------------------------------------------------------------------------
// 1) bits @ mlp_w_in.T + b_in  ->  Y [K, HID]
__global__ __launch_bounds__(256) void k_mlp_in(const float* __restrict__ w_in,
                                                const float* __restrict__ b_in,
                                                float* __restrict__ X) {
    __shared__ float ws_[256 * 12];
    __shared__ float bs_[256];
    int tid = threadIdx.x;
    int h0  = blockIdx.x * 256;
    for (int i = tid; i < 256 * 12; i += 256) ws_[i] = w_in[h0 * 12 + i];
    bs_[tid] = b_in[h0 + tid];
    __syncthreads();
    float w[12];
#pragma unroll
    for (int l = 0; l < 12; l++) w[l] = ws_[tid * 12 + l];
    float bias = bs_[tid];
    int k0 = blockIdx.y * 16;
    for (int kk = 0; kk < 16; kk++) {
        int k = k0 + kk;
        float acc = bias;
#pragma unroll
        for (int l = 0; l < 12; l++)
            if ((k >> (11 - l)) & 1) acc += w[l];
        X[(size_t)k * HID_ + h0 + tid] = acc;
    }
}

// ---------------------------------------------------------------------------
// 2a) BN stats stage 1. grid (64 row-chunks, 4 col-groups), block 256.
// One column per thread, 64 rows ascending — BIT-IDENTICAL per-column chain
// to the validated r8 version. BN stats feed embed feed argmax (knife-edge
// ties, see r7 note at k_argmax_mfma) — do not reorder.
__global__ __launch_bounds__(256) void k_bn_stats1(const float* __restrict__ Y,
                                                   float* __restrict__ part) {
    int b = blockIdx.x;
    int c = blockIdx.y * 256 + threadIdx.x;
    const float* src = Y + ((size_t)b << 6) * HID_ + c;
    float s = 0.f, q = 0.f;
    for (int r = 0; r < 64; r++) {
        float v = src[(size_t)r << 10];
        s += v; q += v * v;
    }
    part[((size_t)b << 10) + c] = s;
    part[65536 + ((size_t)b << 10) + c] = q;
}

// 2b) BN stats stage 2: reduce 64 partials per column -> mean/var. grid 4 x 256
__global__ __launch_bounds__(256) void k_bn_stats2(const float* __restrict__ part,
                                                   float* __restrict__ mv) {
    int c = blockIdx.x * 256 + threadIdx.x;
    float s = 0.f, q = 0.f;
    for (int b = 0; b < 64; b++) {
        s += part[((size_t)b << 10) + c];
        q += part[65536 + ((size_t)b << 10) + c];
    }
    float m = s * (1.f / KK);
    float v = q * (1.f / KK) - m * m;
    mv[c] = m; mv[HID_ + c] = v;
}

// ---------------------------------------------------------------------------
// 3) BN apply + ReLU, emit fp16 hi/lo split pair. grid K*HID/1024, block 256
__global__ __launch_bounds__(256) void k_bn_apply_split(const float* __restrict__ Y,
                                                        const float* __restrict__ mv,
                                                        const float* __restrict__ gamma,
                                                        const float* __restrict__ beta,
                                                        _Float16* __restrict__ Xhi,
                                                        _Float16* __restrict__ Xlo) {
    int i = blockIdx.x * 256 + threadIdx.x;       // float4 index
    int c = (i << 2) & (HID_ - 1);
    float4 x = ((const float4*)Y)[i];
    float4 m = *(const float4*)(mv + c);
    float4 v = *(const float4*)(mv + HID_ + c);
    float4 g = *(const float4*)(gamma + c);
    float4 b = *(const float4*)(beta + c);
    float o[4];
    o[0] = fmaxf(0.f, (x.x - m.x) * (1.f / sqrtf(v.x + 1e-5f)) * g.x + b.x);
    o[1] = fmaxf(0.f, (x.y - m.y) * (1.f / sqrtf(v.y + 1e-5f)) * g.y + b.y);
    o[2] = fmaxf(0.f, (x.z - m.z) * (1.f / sqrtf(v.z + 1e-5f)) * g.z + b.z);
    o[3] = fmaxf(0.f, (x.w - m.w) * (1.f / sqrtf(v.w + 1e-5f)) * g.w + b.w);
    union { _Float16 h[4]; uint2 u; } uh, ul;
#pragma unroll
    for (int j = 0; j < 4; j++) {
        _Float16 h = (_Float16)o[j];
        uh.h[j] = h;
        ul.h[j] = (_Float16)(o[j] - (float)h);
    }
    *(uint2*)(Xhi + ((size_t)i << 2)) = uh.u;
    *(uint2*)(Xlo + ((size_t)i << 2)) = ul.u;
}

// ---------------------------------------------------------------------------
// 4) mid-layer GEMM: C[4096,1024] = (Ahi+Alo) @ (Whi+Wlo)^T + bias.
// r11-VALIDATED schedule restored (r12's pair-step vmcnt(0) drained the
// prefetch queue each pair — counted-vmcnt is the whole point, keep 16/8/0).
// 128x128 tile / 64x64 wave tile / 64B-row LDS; depth-3 prefetch, 4 LDS
// buffers, ONE barrier per K-step (STAGE after the barrier; passing
// barrier(t) proves buf[(t-1)&3] = STAGE target was consumed by all waves).
// Per-element K-chain (t ascending, hh->hl->lh per 32-step, bias after) is
// BIT-IDENTICAL to validated r8/r10/r11.
__global__ __launch_bounds__(256) void k_gemm_mfma3(const _Float16* __restrict__ Ahi,
                                                    const _Float16* __restrict__ Alo,
                                                    const _Float16* __restrict__ Whi,
                                                    const _Float16* __restrict__ Wlo,
                                                    const float* __restrict__ bias,
                                                    float* __restrict__ C) {
    __shared__ __attribute__((aligned(128))) char lds[4 * 32768];
    const int tid = threadIdx.x;
    const int wg = blockIdx.x;            // 256 blocks, m-fastest
    const int m0 = (wg & 31) << 7;
    const int n0 = (wg >> 5) << 7;
    const int wave = tid >> 6, lane = tid & 63;
    const int l15 = lane & 15, quad = lane >> 4;
    const int wm = (wave >> 1) << 6;      // 0 / 64
    const int wn = (wave & 1) << 6;       // 0 / 64

    // staging: each wave stages 32 rows of each region (2 x GL16 per region).
    // LDS region layout per 32KB buffer: Ah[0,8K) Al[8K,16K) Wh[16K,24K) Wl[24K,32K)
    const int rowA = (wave << 5) + (lane >> 2);   // 0..127 across waves
    const int colb = (lane & 3) << 4;             // 0/16/32/48 bytes
    const char* gA_h = (const char*)Ahi + ((size_t)(m0 + rowA) << 11) + colb;
    const char* gA_l = (const char*)Alo + ((size_t)(m0 + rowA) << 11) + colb;
    const char* gW_h = (const char*)Whi + ((size_t)(n0 + rowA) << 11) + colb;
    const char* gW_l = (const char*)Wlo + ((size_t)(n0 + rowA) << 11) + colb;
    const int dA = wave << 11;            // wave-uniform LDS dest byte offset

    int offA[4], offW[4];
#pragma unroll
    for (int i = 0; i < 4; i++) offA[i] = ((wm + (i << 4) + l15) << 6) + (quad << 4);
#pragma unroll
    for (int j = 0; j < 4; j++) offW[j] = ((wn + (j << 4) + l15) << 6) + (quad << 4);

    f4v acc[4][4];
#pragma unroll
    for (int i = 0; i < 4; i++)
#pragma unroll
        for (int j = 0; j < 4; j++) acc[i][j] = (f4v){0.f, 0.f, 0.f, 0.f};

    // +32768 on global src = +16 rows (16 * 2048B); +1024 on LDS dest = 16 rows
#define STG(bufi, tt) do { \
        char* b_ = lds + ((bufi) << 15); int o_ = (tt) << 6; \
        GL16(gA_h + o_,         b_ + dA); \
        GL16(gA_h + 32768 + o_, b_ + dA + 1024); \
        GL16(gA_l + o_,         b_ + 8192 + dA); \
        GL16(gA_l + 32768 + o_, b_ + 8192 + dA + 1024); \
        GL16(gW_h + o_,         b_ + 16384 + dA); \
        GL16(gW_h + 32768 + o_, b_ + 16384 + dA + 1024); \
        GL16(gW_l + o_,         b_ + 24576 + dA); \
        GL16(gW_l + 32768 + o_, b_ + 24576 + dA + 1024); \
    } while (0)

    STG(0, 0); STG(1, 1); STG(2, 2);      // 24 loads in flight per wave
    for (int t = 0; t < 32; ++t) {
        // wait for current tile's 8 loads: outstanding-after = newer tiles only
        if (t <= 29)      asm volatile("s_waitcnt vmcnt(16)" ::: "memory");
        else if (t == 30) asm volatile("s_waitcnt vmcnt(8)"  ::: "memory");
        else              asm volatile("s_waitcnt vmcnt(0)"  ::: "memory");
        __builtin_amdgcn_s_barrier();     // buf[t&3] visible to all waves
        asm volatile("" ::: "memory");    // pin reads/STAGE below the barrier
        if (t + 3 < 32) STG((t + 3) & 3, t + 3);   // overwrites buf[(t-1)&3]
        const char* b = lds + ((size_t)(t & 3) << 15);
        h8v ah[4], al[4];
#pragma unroll
        for (int i = 0; i < 4; i++) {
            ah[i] = *(const h8v*)(b + offA[i]);
            al[i] = *(const h8v*)(b + 8192 + offA[i]);
        }
        __builtin_amdgcn_s_setprio(1);
#pragma unroll
        for (int j = 0; j < 4; j++) {
            h8v bh = *(const h8v*)(b + 16384 + offW[j]);
            h8v bl = *(const h8v*)(b + 24576 + offW[j]);
#pragma unroll
            for (int i = 0; i < 4; i++) {
                acc[i][j] = __builtin_amdgcn_mfma_f32_16x16x32_f16(ah[i], bh, acc[i][j], 0, 0, 0);
                acc[i][j] = __builtin_amdgcn_mfma_f32_16x16x32_f16(ah[i], bl, acc[i][j], 0, 0, 0);
                acc[i][j] = __builtin_amdgcn_mfma_f32_16x16x32_f16(al[i], bh, acc[i][j], 0, 0, 0);
            }
        }
        __builtin_amdgcn_s_setprio(0);
        asm volatile("" ::: "memory");    // reads retired before next barrier
    }
#undef STG

#pragma unroll
    for (int j = 0; j < 4; j++) {
        int col = n0 + wn + (j << 4) + l15;
        float bv = bias[col];
#pragma unroll
        for (int i = 0; i < 4; i++) {
            int row = m0 + wm + (i << 4) + (quad << 2);
#pragma unroll
            for (int r = 0; r < 4; r++)
                C[(size_t)(row + r) * HID_ + col] = acc[i][j][r] + bv;
        }
    }
}

// ---------------------------------------------------------------------------
// 4b) out-layer GEMM (N=64): validated r10 kernel, tile 128x64. Kept for the
// w_out layer only (N=64 can't fill a 128x128 tile). grid 32 (mult of 8).
__global__ __launch_bounds__(256) void k_gemm_mfma2(const _Float16* __restrict__ Ahi,
                                                    const _Float16* __restrict__ Alo,
                                                    const _Float16* __restrict__ Whi,
                                                    const _Float16* __restrict__ Wlo,
                                                    const float* __restrict__ bias,
                                                    float* __restrict__ C,
                                                    int M, int N, int Kd) {
    __shared__ __attribute__((aligned(128))) char lds[2][24576];
    const int tid = threadIdx.x;
    int wg = blockIdx.x;
    const int nwg = gridDim.x;           // multiple of 8
    wg = (wg & 7) * (nwg >> 3) + (wg >> 3);
    const int nx = M >> 7;
    const int m0 = (wg % nx) << 7;
    const int n0 = (wg / nx) << 6;
    const int wave = tid >> 6, lane = tid & 63;
    const int l15 = lane & 15, quad = lane >> 4;
    const int wm = (wave >> 1) << 6;      // 0 / 64
    const int wn = (wave & 1) << 5;       // 0 / 32

    const int pA0 = ((wave << 1) | 0) * 1024 + lane * 16;
    const int pA1 = ((wave << 1) | 1) * 1024 + lane * 16;
    const int pW  = wave * 1024 + lane * 16;
    const int qA0 = pA0 ^ (((pA0 >> 7) & 3) << 4);
    const int qA1 = pA1 ^ (((pA1 >> 7) & 3) << 4);
    const int qW  = pW  ^ (((pW  >> 7) & 3) << 4);
    const size_t krow = (size_t)Kd * 2;
    const char* gAh0 = (const char*)Ahi + (size_t)(m0 + (qA0 >> 6)) * krow + (qA0 & 63);
    const char* gAh1 = (const char*)Ahi + (size_t)(m0 + (qA1 >> 6)) * krow + (qA1 & 63);
    const char* gAl0 = (const char*)Alo + (size_t)(m0 + (qA0 >> 6)) * krow + (qA0 & 63);
    const char* gAl1 = (const char*)Alo + (size_t)(m0 + (qA1 >> 6)) * krow + (qA1 & 63);
    const char* gWh  = (const char*)Whi + (size_t)(n0 + (qW >> 6)) * krow + (qW & 63);
    const char* gWl  = (const char*)Wlo + (size_t)(n0 + (qW >> 6)) * krow + (qW & 63);
    const int dA0 = (wave << 1) * 1024;
    const int dA1 = dA0 + 1024;
    const int dW  = wave * 1024;

    int offA[4], offW[2];
#pragma unroll
    for (int i = 0; i < 4; i++) {
        int r = wm + (i << 4) + l15;
        offA[i] = r * 64 + ((quad ^ ((r >> 1) & 3)) << 4);
    }
#pragma unroll
    for (int j = 0; j < 2; j++) {
        int r = wn + (j << 4) + l15;
        offW[j] = r * 64 + ((quad ^ ((r >> 1) & 3)) << 4);
    }

    f4v acc[4][2];
#pragma unroll
    for (int i = 0; i < 4; i++)
#pragma unroll
        for (int j = 0; j < 2; j++) acc[i][j] = (f4v){0.f, 0.f, 0.f, 0.f};

#define STAGE(bufi, tt) do { \
        char* b_ = lds[bufi]; size_t o_ = (size_t)(tt) << 6; \
        GL16(gAh0 + o_, b_ + dA0); \
        GL16(gAh1 + o_, b_ + dA1); \
        GL16(gAl0 + o_, b_ + 8192 + dA0); \
        GL16(gAl1 + o_, b_ + 8192 + dA1); \
        GL16(gWh  + o_, b_ + 16384 + dW); \
        GL16(gWl  + o_, b_ + 20480 + dW); \
    } while (0)

    STAGE(0, 0);
    const int nt = Kd >> 5;
    for (int t = 0; t < nt; ++t) {
        const int cur = t & 1;
        if (t + 1 < nt) {
            STAGE(cur ^ 1, t + 1);
            asm volatile("s_waitcnt vmcnt(6)" ::: "memory");
        } else {
            asm volatile("s_waitcnt vmcnt(0)" ::: "memory");
        }
        __builtin_amdgcn_s_barrier();
        asm volatile("" ::: "memory");
        const char* b = lds[cur];
        h8v ah[4], al[4], bh[2], bl[2];
#pragma unroll
        for (int i = 0; i < 4; i++) {
            ah[i] = *(const h8v*)(b + offA[i]);
            al[i] = *(const h8v*)(b + 8192 + offA[i]);
        }
#pragma unroll
        for (int j = 0; j < 2; j++) {
            bh[j] = *(const h8v*)(b + 16384 + offW[j]);
            bl[j] = *(const h8v*)(b + 20480 + offW[j]);
        }
        __builtin_amdgcn_s_setprio(1);
#pragma unroll
        for (int i = 0; i < 4; i++)
#pragma unroll
            for (int j = 0; j < 2; j++) {
                acc[i][j] = __builtin_amdgcn_mfma_f32_16x16x32_f16(ah[i], bh[j], acc[i][j], 0, 0, 0);
                acc[i][j] = __builtin_amdgcn_mfma_f32_16x16x32_f16(ah[i], bl[j], acc[i][j], 0, 0, 0);
                acc[i][j] = __builtin_amdgcn_mfma_f32_16x16x32_f16(al[i], bh[j], acc[i][j], 0, 0, 0);
            }
        __builtin_amdgcn_s_setprio(0);
        asm volatile("" ::: "memory");
        __builtin_amdgcn_s_barrier();
    }
#undef STAGE

#pragma unroll
    for (int j = 0; j < 2; j++) {
        int col = n0 + wn + (j << 4) + l15;
        float bv = bias[col];
#pragma unroll
        for (int i = 0; i < 4; i++) {
            int row = m0 + wm + (i << 4) + (quad << 2);
#pragma unroll
            for (int r = 0; r < 4; r++)
                C[(size_t)(row + r) * N + col] = acc[i][j][r] + bv;
        }
    }
}

// ---------------------------------------------------------------------------
// 5) L2-normalize embed rows (in place) + f16 split + eqh = -0.5*||ehat||^2
__global__ __launch_bounds__(256) void k_l2norm(float* __restrict__ E,
                                                float* __restrict__ eqh,
                                                _Float16* __restrict__ Ehi,
                                                _Float16* __restrict__ Elo) {
    int tid = threadIdx.x;
    int row = blockIdx.x * 4 + (tid >> 6);
    int v = tid & 63;
    size_t off = ((size_t)row << 6) + v;
    float x = E[off];
    float ss = x * x;
#pragma unroll
    for (int o = 32; o; o >>= 1) ss += __shfl_xor(ss, o, 64);
    float inv = 1.f / (sqrtf(ss) + 1e-6f);
    float xn = x * inv;
    E[off] = xn;
    _Float16 hh = (_Float16)xn;
    Ehi[off] = hh;
    Elo[off] = (_Float16)(xn - (float)hh);
    if (v == 0) eqh[row] = -0.5f * (ss * inv * inv);
}

// ---------------------------------------------------------------------------
// 6a) ALL fp32->f16 hi/lo weight splits in ONE launch (w_mid 4 layers,
// w_out, proj_w) — same per-element rounding as the old k_wsplit, so the
// chain stays bit-exact. grid 4208 x 256.
__global__ __launch_bounds__(256) void k_wsplit_all(const float* __restrict__ w_mid,
                                                    const float* __restrict__ w_out,
                                                    const float* __restrict__ proj_w,
                                                    _Float16* __restrict__ Wmh,
                                                    _Float16* __restrict__ Wml,
                                                    _Float16* __restrict__ Woh,
                                                    _Float16* __restrict__ Wol,
                                                    _Float16* __restrict__ pwhi,
                                                    _Float16* __restrict__ pwlo) {
    int i = blockIdx.x * 256 + threadIdx.x;
    const float4* src; _Float16 *dh, *dl; int off;
    if (i < 1048576)            { src = (const float4*)w_mid;  dh = Wmh;  dl = Wml;  off = i; }
    else if (i < 1048576+16384) { src = (const float4*)w_out;  dh = Woh;  dl = Wol;  off = i - 1048576; }
    else                        { src = (const float4*)proj_w; dh = pwhi; dl = pwlo; off = i - 1048576 - 16384; }
    float4 w = src[off];
    float wf[4] = {w.x, w.y, w.z, w.w};
    union { _Float16 h[4]; uint2 u; } uh, ul;
#pragma unroll
    for (int j = 0; j < 4; j++) {
        _Float16 h = (_Float16)wf[j];
        uh.h[j] = h;
        ul.h[j] = (_Float16)(wf[j] - (float)h);
    }
    *(uint2*)(dh + ((size_t)off << 2)) = uh.u;
    *(uint2*)(dl + ((size_t)off << 2)) = ul.u;
}

// 6a') convert inv_w -> f16 hi only [d][v] (final projection is not
// argmax-feeding; threshold 81.92 >> f16 error). grid 48 x 256.
// iwh lives in the OVERLAY region (dead Xhi/Xlo) — must stay a LATE launch.
__global__ __launch_bounds__(256) void k_cvt_inv(const float* __restrict__ iw,
                                                 _Float16* __restrict__ iwh) {
    int i = blockIdx.x * 256 + threadIdx.x;       // float4 index, 49152/4 total
    float4 w = ((const float4*)iw)[i];
    union { _Float16 h[4]; uint2 u; } uh;
    uh.h[0] = (_Float16)w.x; uh.h[1] = (_Float16)w.y;
    uh.h[2] = (_Float16)w.z; uh.h[3] = (_Float16)w.w;
    *(uint2*)(iwh + ((size_t)i << 2)) = uh.u;
}

// ---------------------------------------------------------------------------
// 6b) projection GEMM, split-K: Hpart[ks][t][v] = sum_{d in chunk} h_in[b,d,t]*pw[v,d]
// grid (NT/128, 4), block 256 (4 waves, each 32t x 64v). 6 K-steps of 32.
__global__ __launch_bounds__(256) void k_proj_mfma(const float* __restrict__ h_in,
                                                   const _Float16* __restrict__ pwhi,
                                                   const _Float16* __restrict__ pwlo,
                                                   float* __restrict__ Hpart) {
    __shared__ float shA[128 * 33];
    const int tid = threadIdx.x;
    const int t0 = blockIdx.x * 128;
    const int ks = blockIdx.y;            // d-chunk [ks*192, ks*192+192)
    const int b = t0 >> 11;
    const int tloc0 = t0 & (TT_ - 1);
    const int wave = tid >> 6, lane = tid & 63;
    const int l15 = lane & 15, quad = lane >> 4;

    const int dl = tid >> 3;              // 0..31 (d within chunk step)
    const int tg = (tid & 7) << 4;        // 0,16,...,112 (t offset)

    f4v acc[2][4];
#pragma unroll
    for (int i = 0; i < 2; i++)
#pragma unroll
        for (int j = 0; j < 4; j++) acc[i][j] = (f4v){0.f, 0.f, 0.f, 0.f};

    for (int kk = 0; kk < 6; kk++) {
        int dd0 = ks * 192 + kk * 32;
        const float* src = h_in + ((size_t)(b * DD + dd0 + dl) << 11) + tloc0 + tg;
        float4 g0 = *(const float4*)(src);
        float4 g1 = *(const float4*)(src + 4);
        float4 g2 = *(const float4*)(src + 8);
        float4 g3 = *(const float4*)(src + 12);
        __syncthreads();
        float gv[16] = {g0.x, g0.y, g0.z, g0.w, g1.x, g1.y, g1.z, g1.w,
                        g2.x, g2.y, g2.z, g2.w, g3.x, g3.y, g3.z, g3.w};
#pragma unroll
        for (int i = 0; i < 16; i++) shA[(tg + i) * 33 + dl] = gv[i];
        __syncthreads();

        h8v ah[2], al[2];
#pragma unroll
        for (int mt = 0; mt < 2; mt++) {
            const float* ap = &shA[((wave << 5) + (mt << 4) + l15) * 33 + (quad << 3)];
            float4 a0 = *(const float4*)(ap);
            float4 a1 = *(const float4*)(ap + 4);
            float av[8] = {a0.x, a0.y, a0.z, a0.w, a1.x, a1.y, a1.z, a1.w};
#pragma unroll
            for (int j = 0; j < 8; j++) {
                _Float16 h = (_Float16)av[j];
                ah[mt][j] = h;
                al[mt][j] = (_Float16)(av[j] - (float)h);
            }
        }
#pragma unroll
        for (int nt = 0; nt < 4; nt++) {
            size_t wb = (size_t)((nt << 4) + l15) * DD + dd0 + (quad << 3);
            h8v bh = *(const h8v*)(pwhi + wb);
            h8v bl = *(const h8v*)(pwlo + wb);
#pragma unroll
            for (int mt = 0; mt < 2; mt++) {
                acc[mt][nt] = __builtin_amdgcn_mfma_f32_16x16x32_f16(ah[mt], bh, acc[mt][nt], 0, 0, 0);
                acc[mt][nt] = __builtin_amdgcn_mfma_f32_16x16x32_f16(ah[mt], bl, acc[mt][nt], 0, 0, 0);
                acc[mt][nt] = __builtin_amdgcn_mfma_f32_16x16x32_f16(al[mt], bh, acc[mt][nt], 0, 0, 0);
            }
        }
    }
    float* dst = Hpart + ((size_t)ks << 20);   // ks*16384*64
#pragma unroll
    for (int mt = 0; mt < 2; mt++) {
#pragma unroll
        for (int r = 0; r < 4; r++) {
            int t = t0 + (wave << 5) + (mt << 4) + (quad << 2) + r;
#pragma unroll
            for (int nt = 0; nt < 4; nt++)
                dst[((size_t)t << 6) + (nt << 4) + l15] = acc[mt][nt][r];
        }
    }
}

// ---------------------------------------------------------------------------
// 6c) sum 4 partials + bias, L2-normalize, f16 split. grid NT/64, block 256
__global__ __launch_bounds__(256) void k_hnorm(const float* __restrict__ Hpart,
                                               const float* __restrict__ pb,
                                               _Float16* __restrict__ Hhi,
                                               _Float16* __restrict__ Hlo) {
    __shared__ float ssp[4][64];
    int tid = threadIdx.x;
    int tt = tid & 63, vg = tid >> 6;
    int t = blockIdx.x * 64 + tt;
    size_t base = ((size_t)t << 6) + (vg << 4);
    float o[16];
#pragma unroll
    for (int u = 0; u < 4; u++) {
        float4 p0 = *(const float4*)(Hpart + (0u << 20) + base + (u << 2));
        float4 p1 = *(const float4*)(Hpart + (1u << 20) + base + (u << 2));
        float4 p2 = *(const float4*)(Hpart + (2u << 20) + base + (u << 2));
        float4 p3 = *(const float4*)(Hpart + (3u << 20) + base + (u << 2));
        o[u * 4 + 0] = p0.x + p1.x + p2.x + p3.x;
        o[u * 4 + 1] = p0.y + p1.y + p2.y + p3.y;
        o[u * 4 + 2] = p0.z + p1.z + p2.z + p3.z;
        o[u * 4 + 3] = p0.w + p1.w + p2.w + p3.w;
    }
    float sp = 0.f;
#pragma unroll
    for (int j = 0; j < 16; j++) {
        o[j] += pb[(vg << 4) + j];
        sp = fmaf(o[j], o[j], sp);
    }
    ssp[vg][tt] = sp;
    __syncthreads();
    float ss = ssp[0][tt] + ssp[1][tt] + ssp[2][tt] + ssp[3][tt];
    float inv = 1.f / (sqrtf(ss) + 1e-6f);
    union { _Float16 h[8]; uint4 u; } uh0, uh1, ul0, ul1;
#pragma unroll
    for (int j = 0; j < 16; j++) {
        float xn = o[j] * inv;
        _Float16 hh = (_Float16)xn;
        _Float16 ll = (_Float16)(xn - (float)hh);
        if (j < 8) { uh0.h[j] = hh; ul0.h[j] = ll; }
        else       { uh1.h[j - 8] = hh; ul1.h[j - 8] = ll; }
    }
    *(uint4*)(Hhi + base)     = uh0.u;
    *(uint4*)(Hhi + base + 8) = uh1.u;
    *(uint4*)(Hlo + base)     = ul0.u;
    *(uint4*)(Hlo + base + 8) = ul1.u;
}

// ---------------------------------------------------------------------------
// 7) MFMA argmax: s'(t,k) = hhat.ehat + (-0.5*||ehat||^2).
// NOTE: dot MUST be accumulated from zero-init C and q added AFTER — this
// rounding order is bit-matched to the validated r6 kernel. Folding q into
// the C init (r7) perturbed near-ties between codebook rows at distant
// indices and flipped vq_code. Do not reassociate.
// r13: r6/r11 COMPUTE STRUCTURE RESTORED (r12's half-tile killed ILP and
// doubled E traffic — 75us). New: the E tiles (identical for all 4 waves of
// a block) are staged in LDS ONCE per block via global_load_lds, 3-deep,
// counted vmcnt, one barrier/tile; eqh range (1KB) staged once in prologue.
// Rule-21 both-sides XOR swizzle (col ^= (row&7)<<4): linear LDS dest,
// inverse-swizzled SOURCE address, swizzled ds_read -> bank-uniform b128.
// E/q values, MFMA chain order, k-ascending select all BIT-IDENTICAL.
__global__ __launch_bounds__(256, 4) void k_argmax_mfma(const _Float16* __restrict__ Hhi,
                                                        const _Float16* __restrict__ Hlo,
                                                        const _Float16* __restrict__ Ehi,
                                                        const _Float16* __restrict__ Elo,
                                                        const float* __restrict__ eqh,
                                                        float* __restrict__ ps,
                                                        int* __restrict__ pi) {
    // 4 tile-buffers x 4KB (Ehi 2KB | Elo 2KB) + 1KB q
    __shared__ __attribute__((aligned(128))) char elds[4 * 4096 + 1024];
    int tid = threadIdx.x;
    int wave = tid >> 6, lane = tid & 63;
    int l15 = lane & 15, quad = lane >> 4;
    int t0 = blockIdx.x * 256 + wave * 64;
    int kh = blockIdx.y;                  // 0..15, k-range [kh*256, kh*256+256)
    const int kbase = kh << 8;

    // resident H fragments (16 x h8v = 64 VGPR; launch_bounds(,4) caps at 128)
    h8v hh0[4], hh1[4], hl0[4], hl1[4];
#pragma unroll
    for (int s = 0; s < 4; s++) {
        size_t hb = (size_t)(t0 + (s << 4) + l15) * 64 + (quad << 3);
        hh0[s] = *(const h8v*)(Hhi + hb);
        hh1[s] = *(const h8v*)(Hhi + hb + 32);
        hl0[s] = *(const h8v*)(Hlo + hb);
        hl1[s] = *(const h8v*)(Hlo + hb + 32);
    }
    float best[4] = {-1e30f, -1e30f, -1e30f, -1e30f};
    int   idx[4]  = {0, 0, 0, 0};

    // staging geometry: tile tt = E rows [kbase+16*tt, +16), 128B/row.
    // waves 0,1 stage Ehi (2KB), waves 2,3 stage Elo; LDS write is linear
    // (uniform base wave*1024 + lane*16); SOURCE col pre-swizzled.
    const int p    = ((wave & 1) << 10) + lane * 16;   // linear pos in region
    const int srow = p >> 7;                           // 0..15
    const int scol = (p & 127) ^ ((srow & 7) << 4);    // involution
    const char* gsrc0 = (const char*)((wave < 2) ? Ehi : Elo)
                      + (((size_t)kbase + srow) << 7) + scol;
    const int dwave = wave << 10;
#define ASTG(tt) GL16(gsrc0 + ((size_t)(tt) << 11), elds + (((tt) & 3) << 12) + dwave)

    // swizzled ds_read byte offsets (row l15; frag cols 0..63 / 64..127)
    const int rswz = (l15 & 7) << 4;
    const int o_e0 = l15 * 128 + ((quad << 4) ^ rswz);
    const int o_e1 = l15 * 128 + ((64 + (quad << 4)) ^ rswz);

    // prologue: q first (wave 0 only; 1 GL16 = 1KB = eqh[kbase..kbase+255]),
    // then tiles 0..2. vmcnt math: wave0 stream [q,G0,G1,..]; others [G0,G1,..]
    // -> uniform vmcnt(2) at iter 0 completes {q,G0} / {G0}.
    if (wave == 0) GL16((const char*)eqh + ((size_t)kbase << 2), elds + 16384);
    ASTG(0); ASTG(1); ASTG(2);

    for (int t = 0; t < 16; ++t) {
        if (t <= 13)      asm volatile("s_waitcnt vmcnt(2)" ::: "memory");
        else if (t == 14) asm volatile("s_waitcnt vmcnt(1)" ::: "memory");
        else              asm volatile("s_waitcnt vmcnt(0)" ::: "memory");
        __builtin_amdgcn_s_barrier();     // tile t visible; buf[(t-1)&3] consumed
        asm volatile("" ::: "memory");
        if (t + 3 < 16) ASTG(t + 3);      // overwrites buf[(t-1)&3]
        const char* b = elds + ((size_t)(t & 3) << 12);
        h8v ce0 = *(const h8v*)(b + o_e0);
        h8v ce1 = *(const h8v*)(b + o_e1);
        h8v cl0 = *(const h8v*)(b + 2048 + o_e0);
        h8v cl1 = *(const h8v*)(b + 2048 + o_e1);
        float4 cq = *(const float4*)(elds + 16384 + (t << 6) + (quad << 4));
        int k0 = kbase + (t << 4);

        f4v acc[4];
#pragma unroll
        for (int s = 0; s < 4; s++) acc[s] = (f4v){0.f, 0.f, 0.f, 0.f};
        __builtin_amdgcn_s_setprio(1);
#pragma unroll
        for (int s = 0; s < 4; s++) acc[s] = __builtin_amdgcn_mfma_f32_16x16x32_f16(ce0, hh0[s], acc[s], 0, 0, 0);
#pragma unroll
        for (int s = 0; s < 4; s++) acc[s] = __builtin_amdgcn_mfma_f32_16x16x32_f16(ce1, hh1[s], acc[s], 0, 0, 0);
#pragma unroll
        for (int s = 0; s < 4; s++) acc[s] = __builtin_amdgcn_mfma_f32_16x16x32_f16(cl0, hh0[s], acc[s], 0, 0, 0);
#pragma unroll
        for (int s = 0; s < 4; s++) acc[s] = __builtin_amdgcn_mfma_f32_16x16x32_f16(cl1, hh1[s], acc[s], 0, 0, 0);
#pragma unroll
        for (int s = 0; s < 4; s++) acc[s] = __builtin_amdgcn_mfma_f32_16x16x32_f16(ce0, hl0[s], acc[s], 0, 0, 0);
#pragma unroll
        for (int s = 0; s < 4; s++) acc[s] = __builtin_amdgcn_mfma_f32_16x16x32_f16(ce1, hl1[s], acc[s], 0, 0, 0);
        __builtin_amdgcn_s_setprio(0);
        float qv[4] = {cq.x, cq.y, cq.z, cq.w};
#pragma unroll
        for (int r = 0; r < 4; r++) {
            int k = k0 + (quad << 2) + r;
#pragma unroll
            for (int s = 0; s < 4; s++) {
                float sc = acc[s][r] + qv[r];
                if (sc > best[s]) { best[s] = sc; idx[s] = k; }
            }
        }
        asm volatile("" ::: "memory");    // reads retired before next barrier
    }
#undef ASTG

#pragma unroll
    for (int m = 16; m <= 32; m <<= 1) {
#pragma unroll
        for (int s = 0; s < 4; s++) {
            float ob = __shfl_xor(best[s], m, 64);
            int   oi = __shfl_xor(idx[s], m, 64);
            if (ob > best[s] || (ob == best[s] && oi < idx[s])) { best[s] = ob; idx[s] = oi; }
        }
    }
    if (quad == 0) {
#pragma unroll
        for (int s = 0; s < 4; s++) {
            int t = t0 + (s << 4) + l15;
            ps[(size_t)t * 16 + kh] = best[s];
            pi[(size_t)t * 16 + kh] = idx[s];
        }
    }
}

// ---------------------------------------------------------------------------
// 8) merge 16 partials -> code; write vq_code (fp32, masked); gather G16 (f16)
__global__ __launch_bounds__(256) void k_merge(const float* __restrict__ ps,
                                               const int* __restrict__ pi,
                                               const int* __restrict__ mask,
                                               const _Float16* __restrict__ Ehi,
                                               _Float16* __restrict__ G16,
                                               float* __restrict__ outc) {
    __shared__ int codes[256];
    __shared__ int ms[256];
    int tid = threadIdx.x;
    int base = blockIdx.x << 8;
    int t = base + tid;
    float best = ps[(size_t)t * 16];
    int bi = pi[(size_t)t * 16];
#pragma unroll
    for (int s = 1; s < 16; s++) {
        float v = ps[(size_t)t * 16 + s];
        if (v > best) { best = v; bi = pi[(size_t)t * 16 + s]; }
    }
    int m = mask[t];
    codes[tid] = bi;
    ms[tid] = m;
    outc[t] = m ? (float)bi : 0.0f;
    __syncthreads();
    // 64 f16 per row = 8 uint4
    for (int i = tid; i < 256 * 8; i += 256) {
        int r = i >> 3, u = i & 7;
        uint4 e = ms[r] ? ((const uint4*)(Ehi + ((size_t)codes[r] << 6)))[u]
                        : make_uint4(0u, 0u, 0u, 0u);
        ((uint4*)(G16 + ((size_t)(base + r) << 6)))[u] = e;
    }
}

// ---------------------------------------------------------------------------
// 9) final projection: out_q[t][d] = sum_v G16[t][v]*iwh[d][v] + inv_b[d]
// 1-term f16 MFMA (not argmax-feeding; threshold very loose).
// grid (NT/128, DD/64), block 256 (4 waves, each 32t x 64d). K=64 (2 steps).
__global__ __launch_bounds__(256) void k_gemm_out(const _Float16* __restrict__ G16,
                                                  const _Float16* __restrict__ iwh,
                                                  const float* __restrict__ bias,
                                                  float* __restrict__ C) {
    const int tid = threadIdx.x;
    const int t0 = blockIdx.x * 128, n0 = blockIdx.y * 64;
    const int wave = tid >> 6, lane = tid & 63;
    const int l15 = lane & 15, quad = lane >> 4;

    f4v acc[2][4];
#pragma unroll
    for (int i = 0; i < 2; i++)
#pragma unroll
        for (int j = 0; j < 4; j++) acc[i][j] = (f4v){0.f, 0.f, 0.f, 0.f};

#pragma unroll
    for (int ks = 0; ks < 2; ks++) {
        int kk = (ks << 5) + (quad << 3);
        h8v a[2], b[4];
#pragma unroll
        for (int mt = 0; mt < 2; mt++)
            a[mt] = *(const h8v*)(G16 + (size_t)(t0 + (wave << 5) + (mt << 4) + l15) * 64 + kk);
#pragma unroll
        for (int nt = 0; nt < 4; nt++)
            b[nt] = *(const h8v*)(iwh + (size_t)(n0 + (nt << 4) + l15) * 64 + kk);
#pragma unroll
        for (int mt = 0; mt < 2; mt++)
#pragma unroll
            for (int nt = 0; nt < 4; nt++)
                acc[mt][nt] = __builtin_amdgcn_mfma_f32_16x16x32_f16(a[mt], b[nt], acc[mt][nt], 0, 0, 0);
    }
#pragma unroll
    for (int nt = 0; nt < 4; nt++) {
        int col = n0 + (nt << 4) + l15;
        float bv = bias[col];
#pragma unroll
        for (int mt = 0; mt < 2; mt++) {
            int row = t0 + (wave << 5) + (mt << 4) + (quad << 2);
#pragma unroll
            for (int r = 0; r < 4; r++)
                C[(size_t)(row + r) * DD + col] = acc[mt][nt][r] + bv;
        }
    }
}

// ---------------------------------------------------------------------------
extern "C" void kernel_launch(void* const* d_in, const int* in_sizes, int n_in,
                              void* d_out, int out_size, void* d_ws, size_t ws_size,
                              hipStream_t stream) {
    const float* h_in   = (const float*)d_in[0];
    const int*   amask  = (const int*)d_in[1];
    const float* proj_w = (const float*)d_in[2];
    const float* proj_b = (const float*)d_in[3];
    const float* inv_w  = (const float*)d_in[4];
    const float* inv_b  = (const float*)d_in[5];
    const float* w_in   = (const float*)d_in[6];
    const float* b_in   = (const float*)d_in[7];
    const float* w_mid  = (const float*)d_in[8];
    const float* b_mid  = (const float*)d_in[9];
    const float* w_out  = (const float*)d_in[10];
    const float* b_out  = (const float*)d_in[11];
    const float* gamma  = (const float*)d_in[12];
    const float* beta   = (const float*)d_in[13];

    // static region (high-water mark == r8-proven footprint; do NOT extend)
    float*     Y    = (float*)d_ws;                          // K*HID fp32   (16 MB)
    _Float16*  Xhi  = (_Float16*)(Y + (size_t)KK * HID_);    // K*HID fp16   (8 MB)
    _Float16*  Xlo  = Xhi + (size_t)KK * HID_;               // K*HID fp16   (8 MB)
    float*     mv   = (float*)(Xlo + (size_t)KK * HID_);     // 2*HID
    float*     Emb  = mv + 2 * HID_;                         // K*VQ fp32
    float*     eqh  = Emb + (size_t)KK * VQ_;                // K
    float*     spart= eqh + KK;                              // 2*64*1024 stats partials
    _Float16*  pwhi = (_Float16*)(spart + 2 * 65536);        // VQ*DD f16
    _Float16*  pwlo = pwhi + (size_t)VQ_ * DD;               // VQ*DD f16  <- ws END (r8 level)
    // overlays (inside dead Xhi/Xlo region, valid after the out-layer GEMM):
    float*    Hpart = Y;                                     // 4*NT*64 fp32 == K*HID exactly
    _Float16* H16hi = Xhi;                                   // NT*64 f16
    _Float16* H16lo = H16hi + (size_t)NT * VQ_;              // NT*64 f16
    _Float16* E16hi = H16lo + (size_t)NT * VQ_;              // K*64 f16
    _Float16* E16lo = E16hi + (size_t)KK * VQ_;              // K*64 f16
    float*    ps    = (float*)(E16lo + (size_t)KK * VQ_);    // NT*16
    int*      pidx  = (int*)(ps + (size_t)NT * 16);          // NT*16
    _Float16* G16   = (_Float16*)(pidx + (size_t)NT * 16);   // NT*64 f16
    _Float16* iwh   = G16 + (size_t)NT * VQ_;                // DD*VQ f16 (overlay, not ws end)

    float* out_q = (float*)d_out;                            // NT*DD fp32
    float* out_c = out_q + (size_t)NT * DD;                  // NT fp32

    // pre-split weights into the d_out region (dead as scratch until
    // k_gemm_out fully overwrites it at the end). 16.25 MB of 48 MB used.
    _Float16* Wmh = (_Float16*)d_out;                        // 4*HID*HID f16 (8 MB)
    _Float16* Wml = Wmh + (size_t)NMID * HID_ * HID_;        // 4*HID*HID f16 (8 MB)
    _Float16* Woh = Wml + (size_t)NMID * HID_ * HID_;        // VQ*HID f16 (128 KB)
    _Float16* Wol = Woh + (size_t)VQ_ * HID_;                // VQ*HID f16 (128 KB)

    // all fp32->f16 weight splits in one launch (w_mid x4, w_out, proj_w)
    k_wsplit_all<<<4208, 256, 0, stream>>>(w_mid, w_out, proj_w,
                                           Wmh, Wml, Woh, Wol, pwhi, pwlo);

    // codebook MLP (fp16-split MFMA chain, fp32-equivalent precision)
    k_mlp_in<<<dim3(HID_ / 256, KK / 16), 256, 0, stream>>>(w_in, b_in, Y);
    k_bn_stats1<<<dim3(64, 4), 256, 0, stream>>>(Y, spart);
    k_bn_stats2<<<4, 256, 0, stream>>>(spart, mv);
    k_bn_apply_split<<<KK * HID_ / 1024, 256, 0, stream>>>(Y, mv, gamma, beta, Xhi, Xlo);
    for (int i = 0; i < NMID; i++) {
        k_gemm_mfma3<<<(KK / 128) * (HID_ / 128), 256, 0, stream>>>(
            Xhi, Xlo, Wmh + (size_t)i * HID_ * HID_, Wml + (size_t)i * HID_ * HID_,
            b_mid + (size_t)i * HID_, Y);
        k_bn_stats1<<<dim3(64, 4), 256, 0, stream>>>(Y, spart);
        k_bn_stats2<<<4, 256, 0, stream>>>(spart, mv);
        k_bn_apply_split<<<KK * HID_ / 1024, 256, 0, stream>>>(Y, mv,
            gamma + (size_t)(i + 1) * HID_, beta + (size_t)(i + 1) * HID_, Xhi, Xlo);
    }
    k_gemm_mfma2<<<(KK / 128) * (VQ_ / 64), 256, 0, stream>>>(
        Xhi, Xlo, Woh, Wol, b_out, Emb, KK, VQ_, HID_);
    k_l2norm<<<KK / 4, 256, 0, stream>>>(Emb, eqh, E16hi, E16lo);

    // hidden-state path (Xhi/Xlo dead from here; overlay region valid)
    k_cvt_inv<<<VQ_ * DD / 1024, 256, 0, stream>>>(inv_w, iwh);
    k_proj_mfma<<<dim3(NT / 128, 4), 256, 0, stream>>>(h_in, pwhi, pwlo, Hpart);
    k_hnorm<<<NT / 64, 256, 0, stream>>>(Hpart, proj_b, H16hi, H16lo);
    k_argmax_mfma<<<dim3(NT / 256, 16), 256, 0, stream>>>(
        H16hi, H16lo, E16hi, E16lo, eqh, ps, pidx);
    k_merge<<<NT / 256, 256, 0, stream>>>(ps, pidx, amask, E16hi, G16, out_c);
    k_gemm_out<<<dim3(NT / 128, DD / 64), 256, 0, stream>>>(G16, iwh, inv_b, out_q);
}